// Round 11
// baseline (371.900 us; speedup 1.0000x reference)
//
#include <hip/hip_runtime.h>

// Shift_DWConv: depthwise 3x3 conv with power-of-two (DeepShift) weights.
// x: [B=16, N=4096, C=768] f32 channels-last; out same.
// R4: 8192 blk, no reuse   -> 565MB, 3.9 TB/s, 145 us (occ 48%)
// R6: 1024 blk, reg-tile   -> 363MB, 2.4 TB/s, 152 us (occ 25%)
// R7: 2048 blk, +prefetch  -> 314MB, 2.4 TB/s, 131 us (occ 16%)
// Lesson: BW tracks resident waves x outstanding loads, not traffic.
// R8: LDS-tiled. 6144 blocks of 256 thr; stage 18x10x64ch halo tile via a
// 12-deep global_load_dwordx4 register burst (deep MLP), quantize once,
// compute from LDS. L2 amp 1.41x. 46KB LDS -> 3 blk/CU = 12 waves/CU.

#define DIM 768
#define HD  64
#define WD  64
#define BD  16
#define CS  64             // channel slice per block
#define NSL (DIM / CS)     // 12 slices
#define TLW 16             // tile width  (output pixels)
#define TLH 8              // tile height (output pixels)
#define NPIX (HD * WD)
#define LROWS (TLH + 2)    // 10
#define LPX   (TLW + 2)    // 18
#define STG_ELEMS (LROWS * LPX * (CS / 4))   // 2880 f4 elements
#define STG_ITERS ((STG_ELEMS + 255) / 256)  // 12
#define NBLK (4 * 8 * NSL * BD)              // 6144, % 8 == 0

typedef float f32x4 __attribute__((ext_vector_type(4)));

__device__ __forceinline__ float qfix(float x) {
    // round_to_fixed: floor(x * 2^16) * 2^-16, clipped to [-2^15, 2^15 - 1]
    float v = floorf(x * 65536.0f) * 1.52587890625e-05f;
    return fminf(fmaxf(v, -32768.0f), 32767.0f);
}

__device__ __forceinline__ f32x4 q4v(f32x4 v) {
    #pragma unroll
    for (int i = 0; i < 4; ++i) v[i] = qfix(v[i]);
    return v;
}

__device__ __forceinline__ f32x4 fma4(f32x4 a, f32x4 b, f32x4 c) {
    #pragma unroll
    for (int i = 0; i < 4; ++i) c[i] = fmaf(a[i], b[i], c[i]);
    return c;
}

// Pre-kernel: dequantize power-of-two weights once into ws as [9][768]
// (tap-major, coalesced per-tap loads), and fixed-point-quantize bias.
__global__ void wprep_kernel(const float* __restrict__ shift,
                             const float* __restrict__ sgn,
                             const float* __restrict__ bias,
                             float* __restrict__ wbuf,
                             float* __restrict__ bbuf) {
    int i = blockIdx.x * 256 + threadIdx.x;
    if (i < DIM * 9) {
        int c = i / 9;
        int k = i - c * 9;                       // input layout [C][3][3]
        float sr = rintf(fminf(fmaxf(shift[i], -14.0f), 0.0f)); // round(clip)
        float g  = rintf(sgn[i]);
        float sg = (g > 0.0f) ? 1.0f : ((g < 0.0f) ? -1.0f : 0.0f);
        wbuf[k * DIM + c] = exp2f(sr) * sg;      // 2^shift_r * sign_r
    }
    if (i < DIM) bbuf[i] = qfix(bias[i]);
}

// Block = (batch, 64-ch slice, 16w x 8h tile). 256 threads = 16 f4-ch x 16 w.
__global__ __launch_bounds__(256, 3) void dwconv_kernel(
        const float* __restrict__ x,
        const float* __restrict__ wbuf,
        const float* __restrict__ bbuf,
        float* __restrict__ out) {
    __shared__ float lds[LROWS][LPX][CS];        // 46080 B, quantized input

    // Bijective XCD-chunk swizzle: w/h-neighbor tiles (shared halo) -> same XCD L2.
    int nbid = blockIdx.x + 4 * (blockIdx.y + 8 * blockIdx.z);
    int swz  = (nbid & 7) * (NBLK / 8) + (nbid >> 3);
    const int bx = swz & 3;            // 4 w-tiles
    const int by = (swz >> 2) & 7;     // 8 h-tiles
    const int bz = swz >> 5;           // 0..191 = slice + NSL*batch

    const int tid  = threadIdx.x;
    const int c4   = tid & 15;         // f4 channel slot (compute phase)
    const int wloc = tid >> 4;         // 0..15 output column (compute phase)
    const int w0 = bx * TLW, h0 = by * TLH;
    const int cb = (bz % NSL) * CS;    // channel base
    const int b  = bz / NSL;

    // ---- Stage: 12-deep independent load burst -> quantize once -> LDS ----
    f32x4 tmp[STG_ITERS];
    #pragma unroll
    for (int k = 0; k < STG_ITERS; ++k) {
        int idx = tid + k * 256;
        if (idx < STG_ELEMS) {
            int sc  = idx & 15;
            int px  = (idx >> 4) % LPX;
            int row = idx / (16 * LPX);
            int h = h0 - 1 + row, w = w0 - 1 + px;
            bool v = (h >= 0) & (h < HD) & (w >= 0) & (w < WD);
            tmp[k] = v ? q4v(*(const f32x4*)(
                         x + ((size_t)b * NPIX + (size_t)h * WD + w) * DIM
                           + cb + sc * 4))
                       : (f32x4)0.f;
        }
    }
    #pragma unroll
    for (int k = 0; k < STG_ITERS; ++k) {
        int idx = tid + k * 256;
        if (idx < STG_ELEMS) {
            int sc  = idx & 15;
            int px  = (idx >> 4) % LPX;
            int row = idx / (16 * LPX);
            *(f32x4*)&lds[row][px][sc * 4] = tmp[k];
        }
    }

    // Weights/bias for this thread's 4 channels (L2-hot, overlaps barrier).
    f32x4 wk[9];
    #pragma unroll
    for (int k = 0; k < 9; ++k)
        wk[k] = *(const f32x4*)(wbuf + k * DIM + cb + c4 * 4);
    const f32x4 bq = *(const f32x4*)(bbuf + cb + c4 * 4);

    __syncthreads();

    // ---- Compute: rolling 3-row window from LDS ----
    // out(h0+hh, w0+wloc) uses lds rows hh..hh+2, px wloc..wloc+2.
    f32x4 A[3], B[3], C[3];
    #pragma unroll
    for (int i = 0; i < 3; ++i) {
        A[i] = *(const f32x4*)&lds[0][wloc + i][c4 * 4];
        B[i] = *(const f32x4*)&lds[1][wloc + i][c4 * 4];
    }
    float* op = out + ((size_t)b * NPIX + (size_t)h0 * WD + w0 + wloc) * DIM
                    + cb + c4 * 4;
    #pragma unroll
    for (int hh = 0; hh < TLH; ++hh) {
        #pragma unroll
        for (int i = 0; i < 3; ++i)
            C[i] = *(const f32x4*)&lds[hh + 2][wloc + i][c4 * 4];
        f32x4 acc = bq;
        // XLA conv = cross-correlation: tap ky*3+kx hits row h-1+ky, col w-1+kx.
        #pragma unroll
        for (int i = 0; i < 3; ++i) {
            acc = fma4(wk[i],     A[i], acc);
            acc = fma4(wk[3 + i], B[i], acc);
            acc = fma4(wk[6 + i], C[i], acc);
        }
        // Write-once output: nontemporal, don't pollute L2/LLC.
        __builtin_nontemporal_store(acc, (f32x4*)(op + (size_t)hh * WD * DIM));
        #pragma unroll
        for (int i = 0; i < 3; ++i) { A[i] = B[i]; B[i] = C[i]; }
    }
}

extern "C" void kernel_launch(void* const* d_in, const int* in_sizes, int n_in,
                              void* d_out, int out_size, void* d_ws, size_t ws_size,
                              hipStream_t stream) {
    const float* x     = (const float*)d_in[0];
    const float* shift = (const float*)d_in[1];
    const float* sgn   = (const float*)d_in[2];
    const float* bias  = (const float*)d_in[3];
    float* out  = (float*)d_out;
    float* wbuf = (float*)d_ws;        // 9*768 floats
    float* bbuf = wbuf + 9 * DIM;      // 768 floats  (30 KB < ws_size)

    wprep_kernel<<<(DIM * 9 + 255) / 256, 256, 0, stream>>>(shift, sgn, bias, wbuf, bbuf);

    dim3 grid(4, 8, NSL * BD);         // 4 x 8 x 192 = 6144 blocks
    dwconv_kernel<<<grid, 256, 0, stream>>>(x, wbuf, bbuf, out);
}